// Round 2
// baseline (4333.287 us; speedup 1.0000x reference)
//
#include <hip/hip_runtime.h>
#include <hip/hip_bf16.h>
#include <math.h>

#define C 256
#define K 9
#define BM 32
#define LDS_STRIDE (C + 4)   // pad 4 floats: row stride 1040 B (16B-aligned, breaks pow2 bank stride)

__device__ __forceinline__ float gelu_exact(float x) {
    return 0.5f * x * (1.0f + erff(x * 0.70710678118654752f));
}

// ---- mask dtype auto-detect ------------------------------------------------
// Scans the first nbytes bytes of the mask buffer (safe: nbytes = N*K <= real
// buffer size for bool(1B)/int32(4B)/float32(4B) encodings alike).
// cnt[0] |= 1 if any nonzero byte at i%4==0; cnt[1] |= 1 if any at i%4 in {1,2}.
// bool bytes:   cnt0=1, cnt1=1   (dense 0/1 bytes)
// int32 0/1:    cnt0=1, cnt1=0   (low byte only)
// float32 1.0f: cnt0=0, cnt1=1   (0x3f800000: byte2=0x80)
__global__ void detect_mask_kernel(const unsigned char* __restrict__ mb, int nbytes,
                                   unsigned int* __restrict__ cnt) {
    unsigned int l0 = 0, l12 = 0;
    for (int i = blockIdx.x * blockDim.x + threadIdx.x; i < nbytes;
         i += blockDim.x * gridDim.x) {
        unsigned char v = mb[i];
        if (v) {
            int r = i & 3;
            if (r == 0) l0 = 1;
            else if (r < 3) l12 = 1;
        }
    }
    unsigned long long b0 = __ballot(l0 != 0);
    unsigned long long b1 = __ballot(l12 != 0);
    if ((threadIdx.x & 63) == 0) {
        if (b0) atomicOr(&cnt[0], 1u);
        if (b1) atomicOr(&cnt[1], 1u);
    }
}

// One fused sparse-conv + LayerNorm (+ optional residual) + GELU pass.
// Block: 256 threads = 4 waves. Tile: BM=32 output rows x 256 cols.
// Wave w owns rows 8w..8w+7; lane owns 4 consecutive cols. Each thread: 8x4 register tile.
template<bool PHASE2>
__global__ __launch_bounds__(256, 3)
void conv_ln_gelu(const float* __restrict__ src,     // [N,C] features to gather
                  const float* __restrict__ W,       // [K,C,C]
                  const float* __restrict__ gamma,   // [C]
                  const float* __restrict__ beta,    // [C]
                  const int* __restrict__ nbr,       // [N,K]
                  const void* __restrict__ mask,     // [N,K] encoding per mflags
                  const unsigned int* __restrict__ mflags, // [2] from detect_mask_kernel
                  const float* __restrict__ resid,   // [N,C] (PHASE2 only)
                  float* __restrict__ dst,           // [N,C]
                  int N)
{
    __shared__ float A[BM][LDS_STRIDE];

    const int tid  = threadIdx.x;
    const int n0   = blockIdx.x * BM;
    // staging mapping: 8 threads per row, each loads 8 float4 (32 floats)
    const int srow = tid >> 3;     // 0..31
    const int sq   = tid & 7;      // 0..7
    // compute mapping
    const int rg   = tid >> 6;     // wave id 0..3 -> rows rg*8..rg*8+7
    const int c0   = (tid & 63) * 4;

    // mask encoding: bool-bytes iff nonzero seen at both i%4==0 and i%4 in {1,2}
    const bool mbool = (mflags[0] != 0u) && (mflags[1] != 0u);
    const unsigned char* mask8  = (const unsigned char*)mask;
    const unsigned int*  mask32 = (const unsigned int*)mask;

    float acc[8][4];
    #pragma unroll
    for (int m = 0; m < 8; ++m)
        #pragma unroll
        for (int j = 0; j < 4; ++j) acc[m][j] = 0.0f;

    // ---- gather row pointer + mask for a given k ----
    auto gather_meta = [&](int k, const float4*& p, bool& mk) {
        mk = false; p = nullptr;
        int row = n0 + srow;
        if (row < N) {
            size_t e = (size_t)row * K + k;
            bool mv = mbool ? (mask8[e] != 0) : (mask32[e] != 0u);
            if (mv) {
                mk = true;
                p = (const float4*)(src + (size_t)nbr[e] * C);
            }
        }
    };

    float4 pf[8];
    // prologue: gather k=0
    {
        const float4* p; bool mk;
        gather_meta(0, p, mk);
        if (mk) {
            #pragma unroll
            for (int j = 0; j < 8; ++j) pf[j] = p[sq + j * 8];
        } else {
            float4 z = {0.f, 0.f, 0.f, 0.f};
            #pragma unroll
            for (int j = 0; j < 8; ++j) pf[j] = z;
        }
        #pragma unroll
        for (int j = 0; j < 8; ++j)
            *(float4*)&A[srow][(sq + j * 8) * 4] = pf[j];
    }
    __syncthreads();

    for (int k = 0; k < K; ++k) {
        // issue next-k gather loads early: they retire while we compute k
        bool mk_n = false;
        if (k + 1 < K) {
            const float4* p;
            gather_meta(k + 1, p, mk_n);
            if (mk_n) {
                #pragma unroll
                for (int j = 0; j < 8; ++j) pf[j] = p[sq + j * 8];
            }
        }

        // ---- compute: acc += A_tile(32x256) * W[k](256x256) restricted to our 8x4 ----
        const float* Wk = W + (size_t)k * C * C;
        const int rbase = rg * 8;
        for (int kk4 = 0; kk4 < C / 4; ++kk4) {
            const float* wrow = Wk + (size_t)(kk4 * 4) * C + c0;
            float4 b0 = *(const float4*)(wrow);
            float4 b1 = *(const float4*)(wrow + C);
            float4 b2 = *(const float4*)(wrow + 2 * C);
            float4 b3 = *(const float4*)(wrow + 3 * C);
            #pragma unroll
            for (int m = 0; m < 8; ++m) {
                float4 a = *(const float4*)&A[rbase + m][kk4 * 4];
                acc[m][0] = fmaf(a.w, b3.x, fmaf(a.z, b2.x, fmaf(a.y, b1.x, fmaf(a.x, b0.x, acc[m][0]))));
                acc[m][1] = fmaf(a.w, b3.y, fmaf(a.z, b2.y, fmaf(a.y, b1.y, fmaf(a.x, b0.y, acc[m][1]))));
                acc[m][2] = fmaf(a.w, b3.z, fmaf(a.z, b2.z, fmaf(a.y, b1.z, fmaf(a.x, b0.z, acc[m][2]))));
                acc[m][3] = fmaf(a.w, b3.w, fmaf(a.z, b2.w, fmaf(a.y, b1.w, fmaf(a.x, b0.w, acc[m][3]))));
            }
        }

        __syncthreads();                 // everyone done reading A for k
        if (k + 1 < K) {
            if (mk_n) {
                #pragma unroll
                for (int j = 0; j < 8; ++j)
                    *(float4*)&A[srow][(sq + j * 8) * 4] = pf[j];
            } else {
                float4 z = {0.f, 0.f, 0.f, 0.f};
                #pragma unroll
                for (int j = 0; j < 8; ++j)
                    *(float4*)&A[srow][(sq + j * 8) * 4] = z;
            }
            __syncthreads();             // A staged for k+1
        }
    }

    // ---- epilogue: per-row LayerNorm (+residual) + GELU ----
    const float4 gm = *(const float4*)(gamma + c0);
    const float4 bt = *(const float4*)(beta + c0);
    const float inv_c = 1.0f / (float)C;

    #pragma unroll
    for (int m = 0; m < 8; ++m) {
        int row = n0 + rg * 8 + m;
        float s1 = acc[m][0] + acc[m][1] + acc[m][2] + acc[m][3];
        float s2 = acc[m][0] * acc[m][0] + acc[m][1] * acc[m][1]
                 + acc[m][2] * acc[m][2] + acc[m][3] * acc[m][3];
        #pragma unroll
        for (int off = 32; off > 0; off >>= 1) {
            s1 += __shfl_xor(s1, off, 64);
            s2 += __shfl_xor(s2, off, 64);
        }
        float mu  = s1 * inv_c;
        float var = s2 * inv_c - mu * mu;
        float rs  = rsqrtf(var + 1e-6f);

        if (row < N) {
            float4 rv = {0.f, 0.f, 0.f, 0.f};
            if (PHASE2) rv = *(const float4*)(resid + (size_t)row * C + c0);
            float o[4];
            float g_[4] = {gm.x, gm.y, gm.z, gm.w};
            float b_[4] = {bt.x, bt.y, bt.z, bt.w};
            float r_[4] = {rv.x, rv.y, rv.z, rv.w};
            #pragma unroll
            for (int j = 0; j < 4; ++j) {
                float x = (acc[m][j] - mu) * rs * g_[j] + b_[j];
                if (PHASE2) x += r_[j];
                o[j] = gelu_exact(x);
            }
            float4 ov = {o[0], o[1], o[2], o[3]};
            *(float4*)(dst + (size_t)row * C + c0) = ov;
        }
    }
}

extern "C" void kernel_launch(void* const* d_in, const int* in_sizes, int n_in,
                              void* d_out, int out_size, void* d_ws, size_t ws_size,
                              hipStream_t stream) {
    const float* feats = (const float*)d_in[0];
    const float* W1    = (const float*)d_in[1];
    const float* g1    = (const float*)d_in[2];
    const float* b1    = (const float*)d_in[3];
    const float* W2    = (const float*)d_in[4];
    const float* g2    = (const float*)d_in[5];
    const float* b2    = (const float*)d_in[6];
    const int*   nbr   = (const int*)d_in[7];
    const void*  mask  = (const void*)d_in[8];

    const int N = in_sizes[0] / C;

    unsigned int* mflags = (unsigned int*)d_ws;            // [2] detection flags
    float* h1 = (float*)((char*)d_ws + 256);               // [N, C] intermediate
    float* out = (float*)d_out;

    hipMemsetAsync(mflags, 0, 2 * sizeof(unsigned int), stream);
    detect_mask_kernel<<<256, 256, 0, stream>>>((const unsigned char*)mask, N * K, mflags);

    const int grid = (N + BM - 1) / BM;
    conv_ln_gelu<false><<<grid, 256, 0, stream>>>(feats, W1, g1, b1, nbr, mask, mflags, nullptr, h1, N);
    conv_ln_gelu<true ><<<grid, 256, 0, stream>>>(h1,    W2, g2, b2, nbr, mask, mflags, feats,  out, N);
}

// Round 3
// 669.488 us; speedup vs baseline: 6.4725x; 6.4725x over previous
//
#include <hip/hip_runtime.h>
#include <hip/hip_bf16.h>
#include <math.h>

#define C 256
#define K 9
#define BM 64
#define NKSTEP 72          // 2304 / 32
#define HSTEPS 18          // 9 taps * 2 halves of 128 ch

typedef __attribute__((ext_vector_type(8))) short bf16x8;
typedef __attribute__((ext_vector_type(4))) float f32x4;

__device__ __forceinline__ unsigned short f2bf(float f) {
    unsigned int u = __float_as_uint(f);
    unsigned int r = (u + 0x7fffu + ((u >> 16) & 1u)) >> 16;
    return (unsigned short)r;
}

__device__ __forceinline__ float gelu_exact(float x) {
    return 0.5f * x * (1.0f + erff(x * 0.70710678118654752f));
}

// ---- mask dtype auto-detect (proven in R2) ---------------------------------
__global__ void detect_mask_kernel(const unsigned char* __restrict__ mb, int nbytes,
                                   unsigned int* __restrict__ cnt) {
    unsigned int l0 = 0, l12 = 0;
    for (int i = blockIdx.x * blockDim.x + threadIdx.x; i < nbytes;
         i += blockDim.x * gridDim.x) {
        unsigned char v = mb[i];
        if (v) {
            int r = i & 3;
            if (r == 0) l0 = 1;
            else if (r < 3) l12 = 1;
        }
    }
    unsigned long long b0 = __ballot(l0 != 0);
    unsigned long long b1 = __ballot(l12 != 0);
    if ((threadIdx.x & 63) == 0) {
        if (b0) atomicOr(&cnt[0], 1u);
        if (b1) atomicOr(&cnt[1], 1u);
    }
}

// ---- pack W[K][C][C] fp32 -> bf16 MFMA B-fragment order --------------------
// Wp[((kkg*16 + ctg)*64 + lane)*8 + j] = bf16(W[tap][kkg%8*32 + (lane>>4)*8 + j][ctg*16 + (lane&15)])
__global__ void pack_w(const float* __restrict__ W, unsigned short* __restrict__ Wp) {
    int id = blockIdx.x * blockDim.x + threadIdx.x;
    if (id >= NKSTEP * 16 * 64) return;
    int lane = id & 63;
    int ctg  = (id >> 6) & 15;
    int kkg  = id >> 10;                      // 0..71
    int tap  = kkg >> 3;
    int c    = (kkg & 7) * 32 + ((lane >> 4) << 3);
    int d    = ctg * 16 + (lane & 15);
    const float* src = W + ((size_t)tap * C + c) * C + d;
    unsigned int w[4];
    #pragma unroll
    for (int i = 0; i < 4; ++i) {
        unsigned short lo = f2bf(src[(size_t)(2 * i) * C]);
        unsigned short hi = f2bf(src[(size_t)(2 * i + 1) * C]);
        w[i] = (unsigned int)lo | ((unsigned int)hi << 16);
    }
    uint4 v = {w[0], w[1], w[2], w[3]};
    *(uint4*)(Wp + (size_t)id * 8) = v;
}

// ---- fused sparse-conv (bf16 MFMA) + LayerNorm (+residual) + GELU ----------
// Block 256 thr = 4 waves. Tile 64 rows x 256 cols; wave wv owns cols wv*64..+64.
// LDS A: [2 buf][64 rows][128 ch] bf16, XOR-swizzled: stored c16 = logical c16 ^ (row&7).
template<int PHASE>
__global__ __launch_bounds__(256, 2)
void conv_mfma(const float* __restrict__ srcf,        // PHASE1: feats fp32 [N,C]
               const char* __restrict__ gbase,        // PHASE2: ws base (zero@0, h1 bf16 @512)
               const unsigned short* __restrict__ Wp, // packed bf16 W
               const float* __restrict__ gamma, const float* __restrict__ beta,
               const int* __restrict__ nbr, const void* __restrict__ mask,
               const unsigned int* __restrict__ mflags,
               const float* __restrict__ resid,       // PHASE2: feats fp32
               void* __restrict__ dst,                // PHASE1: ushort* h1; PHASE2: float* out
               int N)
{
    __shared__ __align__(16) unsigned short Abuf[2][BM * 128];  // 32 KB
    __shared__ unsigned int offs[K][BM];                        // gather byte offsets
    __shared__ float part[BM][8];                               // [row][wave*2 + {s1,s2}]

    const int tid  = threadIdx.x;
    const int lane = tid & 63;
    const int wv   = tid >> 6;
    const int n0   = blockIdx.x * BM;

    // ---- gather metadata ----
    const bool mbool = (mflags[0] != 0u) && (mflags[1] != 0u);
    const unsigned char* mask8  = (const unsigned char*)mask;
    const unsigned int*  mask32 = (const unsigned int*)mask;
    for (int e = tid; e < K * BM; e += 256) {
        int tap = e >> 6;             // e / BM
        int r   = e & (BM - 1);
        int row = n0 + r;
        unsigned int off = (PHASE == 1) ? 0xFFFFFFFFu : 0u;   // masked: sentinel / zero page
        if (row < N) {
            size_t ei = (size_t)row * K + tap;
            bool mv = mbool ? (mask8[ei] != 0) : (mask32[ei] != 0u);
            if (mv) off = (PHASE == 1) ? (unsigned int)nbr[ei] * 1024u
                                       : 512u + (unsigned int)nbr[ei] * 512u;
        }
        offs[tap][r] = off;
    }
    __syncthreads();

    f32x4 acc[4][4];
    #pragma unroll
    for (int rt = 0; rt < 4; ++rt)
        #pragma unroll
        for (int ct = 0; ct < 4; ++ct)
            acc[rt][ct] = (f32x4){0.f, 0.f, 0.f, 0.f};

    // ---- PHASE1 reg staging state ----
    float4 pre[8];
    bool pmask = true;

    // issue gathered fp32 loads for stage s (row = tid>>2, 4 c16-slots each)
    auto issue1 = [&](int s) {
        int tap = s >> 1; int h = (s & 1) * 512;      // fp32 byte offset of half
        int r = tid >> 2, q = tid & 3;
        unsigned int off = offs[tap][r];
        pmask = (off == 0xFFFFFFFFu);
        if (!pmask) {
            const char* base = (const char*)srcf + off + h + q * 128;
            #pragma unroll
            for (int i = 0; i < 4; ++i) {
                pre[i * 2]     = *(const float4*)(base + i * 32);
                pre[i * 2 + 1] = *(const float4*)(base + i * 32 + 16);
            }
        }
    };
    // convert + swizzled ds_write of the pre-loaded stage into buf b
    auto write1 = [&](int b) {
        int r = tid >> 2, q = tid & 3;
        #pragma unroll
        for (int i = 0; i < 4; ++i) {
            int c16 = q * 4 + i;
            uint4 v;
            if (pmask) {
                v = (uint4){0u, 0u, 0u, 0u};
            } else {
                float4 a = pre[i * 2], bvec = pre[i * 2 + 1];
                v.x = (unsigned int)f2bf(a.x) | ((unsigned int)f2bf(a.y) << 16);
                v.y = (unsigned int)f2bf(a.z) | ((unsigned int)f2bf(a.w) << 16);
                v.z = (unsigned int)f2bf(bvec.x) | ((unsigned int)f2bf(bvec.y) << 16);
                v.w = (unsigned int)f2bf(bvec.z) | ((unsigned int)f2bf(bvec.w) << 16);
            }
            *(uint4*)(&Abuf[b][r * 128 + ((c16 ^ (r & 7)) * 8)]) = v;
        }
    };

    // PHASE2: async global_load_lds staging with pre-swizzled per-lane source
    auto stage2 = [&](int s, int b) {
        int tap = s >> 1; int h = (s & 1) * 256;      // bf16 byte offset of half
        #pragma unroll
        for (int i = wv * 4; i < wv * 4 + 4; ++i) {   // 4 instrs/wave, 1 KB each (4 rows)
            int r = i * 4 + (lane >> 4);
            int c16s = ((lane & 15) ^ (r & 7)) * 16;
            const char* g = gbase + offs[tap][r] + h + c16s;
            __builtin_amdgcn_global_load_lds((const __attribute__((address_space(1))) void*)g,
                (__attribute__((address_space(3))) void*)(&Abuf[b][i * 512]), 16, 0, 0);
        }
    };

    // one 128-ch stage of MFMA: 4 k-steps x (4 rt x 4 ct)
    auto compute = [&](int s, int p) {
        #pragma unroll
        for (int kk = 0; kk < 4; ++kk) {
            int kkg = s * 4 + kk;
            bf16x8 bfr[4], afr[4];
            #pragma unroll
            for (int ct = 0; ct < 4; ++ct)
                bfr[ct] = *(const bf16x8*)(Wp + (((size_t)kkg * 16 + (wv * 4 + ct)) * 64 + lane) * 8);
            #pragma unroll
            for (int rt = 0; rt < 4; ++rt) {
                int r = rt * 16 + (lane & 15);
                int c16 = kk * 4 + (lane >> 4);
                afr[rt] = *(const bf16x8*)(&Abuf[p][r * 128 + ((c16 ^ (r & 7)) * 8)]);
            }
            #pragma unroll
            for (int rt = 0; rt < 4; ++rt)
                #pragma unroll
                for (int ct = 0; ct < 4; ++ct)
                    acc[rt][ct] = __builtin_amdgcn_mfma_f32_16x16x32_bf16(afr[rt], bfr[ct], acc[rt][ct], 0, 0, 0);
        }
    };

    // ---- pipelined main loop ----
    int p = 0;
    if (PHASE == 1) {
        issue1(0);
        write1(0);
        __syncthreads();
        for (int s = 0; s < HSTEPS; ++s) {
            if (s + 1 < HSTEPS) issue1(s + 1);
            compute(s, p);
            __syncthreads();
            if (s + 1 < HSTEPS) {
                write1(p ^ 1);
                __syncthreads();
            }
            p ^= 1;
        }
    } else {
        stage2(0, 0);
        __syncthreads();                      // compiler drains vmcnt before barrier
        for (int s = 0; s < HSTEPS; ++s) {
            if (s + 1 < HSTEPS) stage2(s + 1, p ^ 1);
            compute(s, p);
            __syncthreads();
            p ^= 1;
        }
    }

    // ---- LayerNorm partials: per-wave 64-col sums per row ----
    #pragma unroll
    for (int rt = 0; rt < 4; ++rt) {
        #pragma unroll
        for (int jj = 0; jj < 4; ++jj) {
            float p1 = 0.f, p2 = 0.f;
            #pragma unroll
            for (int ct = 0; ct < 4; ++ct) {
                float v = acc[rt][ct][jj];
                p1 += v; p2 += v * v;
            }
            #pragma unroll
            for (int off = 1; off < 16; off <<= 1) {
                p1 += __shfl_xor(p1, off, 64);
                p2 += __shfl_xor(p2, off, 64);
            }
            if ((lane & 15) == 0) {
                int row = rt * 16 + (lane >> 4) * 4 + jj;
                part[row][wv * 2]     = p1;
                part[row][wv * 2 + 1] = p2;
            }
        }
    }
    __syncthreads();

    // ---- finalize: LN + (residual) + GELU + store ----
    float gm[4], bt[4];
    #pragma unroll
    for (int ct = 0; ct < 4; ++ct) {
        int col = wv * 64 + ct * 16 + (lane & 15);
        gm[ct] = gamma[col]; bt[ct] = beta[col];
    }
    const float inv_c = 1.0f / 256.0f;
    #pragma unroll
    for (int rt = 0; rt < 4; ++rt) {
        #pragma unroll
        for (int jj = 0; jj < 4; ++jj) {
            int row = rt * 16 + (lane >> 4) * 4 + jj;
            float t1 = part[row][0] + part[row][2] + part[row][4] + part[row][6];
            float t2 = part[row][1] + part[row][3] + part[row][5] + part[row][7];
            float mu  = t1 * inv_c;
            float var = t2 * inv_c - mu * mu;
            float rs  = rsqrtf(var + 1e-6f);
            int grow = n0 + row;
            if (grow < N) {
                #pragma unroll
                for (int ct = 0; ct < 4; ++ct) {
                    int col = wv * 64 + ct * 16 + (lane & 15);
                    float x = (acc[rt][ct][jj] - mu) * rs * gm[ct] + bt[ct];
                    if (PHASE == 2) x += resid[(size_t)grow * C + col];
                    float o = gelu_exact(x);
                    if (PHASE == 1) ((unsigned short*)dst)[(size_t)grow * C + col] = f2bf(o);
                    else            ((float*)dst)[(size_t)grow * C + col] = o;
                }
            }
        }
    }
}

extern "C" void kernel_launch(void* const* d_in, const int* in_sizes, int n_in,
                              void* d_out, int out_size, void* d_ws, size_t ws_size,
                              hipStream_t stream) {
    const float* feats = (const float*)d_in[0];
    const float* W1    = (const float*)d_in[1];
    const float* g1    = (const float*)d_in[2];
    const float* b1    = (const float*)d_in[3];
    const float* W2    = (const float*)d_in[4];
    const float* g2    = (const float*)d_in[5];
    const float* b2    = (const float*)d_in[6];
    const int*   nbr   = (const int*)d_in[7];
    const void*  mask  = (const void*)d_in[8];

    const int N = in_sizes[0] / C;

    // ws layout: [zero page 512B][h1 bf16 N*C*2][Wp1 2.36MB/2][Wp2][flags]
    char* ws = (char*)d_ws;
    unsigned short* h1  = (unsigned short*)(ws + 512);
    size_t h1_bytes = (size_t)N * C * 2;                 // 51,200,000
    unsigned short* Wp1 = (unsigned short*)(ws + 512 + h1_bytes);
    size_t wp_bytes = (size_t)NKSTEP * 16 * 64 * 8 * 2;  // 1,179,648
    unsigned short* Wp2 = (unsigned short*)(ws + 512 + h1_bytes + wp_bytes);
    unsigned int* mflags = (unsigned int*)(ws + 512 + h1_bytes + 2 * wp_bytes);

    hipMemsetAsync(ws, 0, 512, stream);                  // zero page for masked gathers
    hipMemsetAsync(mflags, 0, 2 * sizeof(unsigned int), stream);
    detect_mask_kernel<<<256, 256, 0, stream>>>((const unsigned char*)mask, N * K, mflags);
    pack_w<<<(NKSTEP * 16 * 64 + 255) / 256, 256, 0, stream>>>(W1, Wp1);
    pack_w<<<(NKSTEP * 16 * 64 + 255) / 256, 256, 0, stream>>>(W2, Wp2);

    const int grid = (N + BM - 1) / BM;
    conv_mfma<1><<<grid, 256, 0, stream>>>(feats, nullptr, Wp1, g1, b1, nbr, mask, mflags,
                                           nullptr, (void*)h1, N);
    conv_mfma<2><<<grid, 256, 0, stream>>>(nullptr, ws, Wp2, g2, b2, nbr, mask, mflags,
                                           feats, d_out, N);
}

// Round 4
// 627.635 us; speedup vs baseline: 6.9041x; 1.0667x over previous
//
#include <hip/hip_runtime.h>
#include <hip/hip_bf16.h>
#include <math.h>

#define C 256
#define K 9
#define BM 64
#define NKSTEP 72          // 2304 / 32
#define HSTEPS 18          // 9 taps * 2 halves of 128 ch
#define NBUF 3             // gather prefetch distance 2

typedef __attribute__((ext_vector_type(8))) short bf16x8;
typedef __attribute__((ext_vector_type(4))) float f32x4;

__device__ __forceinline__ unsigned short f2bf(float f) {
    unsigned int u = __float_as_uint(f);
    unsigned int r = (u + 0x7fffu + ((u >> 16) & 1u)) >> 16;
    return (unsigned short)r;
}

__device__ __forceinline__ float gelu_exact(float x) {
    return 0.5f * x * (1.0f + erff(x * 0.70710678118654752f));
}

// ---- mask dtype auto-detect (proven R2/R3) ---------------------------------
__global__ void detect_mask_kernel(const unsigned char* __restrict__ mb, int nbytes,
                                   unsigned int* __restrict__ cnt) {
    unsigned int l0 = 0, l12 = 0;
    for (int i = blockIdx.x * blockDim.x + threadIdx.x; i < nbytes;
         i += blockDim.x * gridDim.x) {
        unsigned char v = mb[i];
        if (v) {
            int r = i & 3;
            if (r == 0) l0 = 1;
            else if (r < 3) l12 = 1;
        }
    }
    unsigned long long b0 = __ballot(l0 != 0);
    unsigned long long b1 = __ballot(l12 != 0);
    if ((threadIdx.x & 63) == 0) {
        if (b0) atomicOr(&cnt[0], 1u);
        if (b1) atomicOr(&cnt[1], 1u);
    }
}

// ---- feats fp32 -> bf16, vectorized (8/thread) -----------------------------
__global__ void convert_feats(const float* __restrict__ in, unsigned short* __restrict__ out, int n8) {
    int i = blockIdx.x * blockDim.x + threadIdx.x;
    if (i >= n8) return;
    const float4* p = (const float4*)(in + (size_t)i * 8);
    float4 a = p[0], b = p[1];
    uint4 v;
    v.x = (unsigned int)f2bf(a.x) | ((unsigned int)f2bf(a.y) << 16);
    v.y = (unsigned int)f2bf(a.z) | ((unsigned int)f2bf(a.w) << 16);
    v.z = (unsigned int)f2bf(b.x) | ((unsigned int)f2bf(b.y) << 16);
    v.w = (unsigned int)f2bf(b.z) | ((unsigned int)f2bf(b.w) << 16);
    *(uint4*)(out + (size_t)i * 8) = v;
}

// ---- pack W[K][C][C] fp32 -> bf16 MFMA B-fragment order (proven R3) --------
__global__ void pack_w(const float* __restrict__ W, unsigned short* __restrict__ Wp) {
    int id = blockIdx.x * blockDim.x + threadIdx.x;
    if (id >= NKSTEP * 16 * 64) return;
    int lane = id & 63;
    int ctg  = (id >> 6) & 15;
    int kkg  = id >> 10;
    int tap  = kkg >> 3;
    int c    = (kkg & 7) * 32 + ((lane >> 4) << 3);
    int d    = ctg * 16 + (lane & 15);
    const float* src = W + ((size_t)tap * C + c) * C + d;
    unsigned int w[4];
    #pragma unroll
    for (int i = 0; i < 4; ++i) {
        unsigned short lo = f2bf(src[(size_t)(2 * i) * C]);
        unsigned short hi = f2bf(src[(size_t)(2 * i + 1) * C]);
        w[i] = (unsigned int)lo | ((unsigned int)hi << 16);
    }
    uint4 v = {w[0], w[1], w[2], w[3]};
    *(uint4*)(Wp + (size_t)id * 8) = v;
}

// ---- fused sparse-conv (bf16 MFMA) + LN (+residual) + GELU -----------------
// Both phases gather bf16 rows (512 B) from gbase: zero page @0, rows @512+idx*512.
// 3-deep LDS rotation, raw s_barrier + counted vmcnt(4): stage s+2 gathers stay
// in flight across barriers (T3/T4). One barrier per stage.
template<int PHASE>
__global__ __launch_bounds__(256, 3)
void conv_mfma(const char* __restrict__ gbase,
               const unsigned short* __restrict__ Wp,
               const float* __restrict__ gamma, const float* __restrict__ beta,
               const int* __restrict__ nbr, const void* __restrict__ mask,
               const unsigned int* __restrict__ mflags,
               const float* __restrict__ resid,        // PHASE2: fp32 feats
               void* __restrict__ dst,                 // PHASE1: ushort* h1; PHASE2: float* out
               int N)
{
    __shared__ __align__(16) unsigned short Abuf[NBUF][BM * 128];  // 48 KB
    __shared__ unsigned int offs[K][BM];
    __shared__ float part[BM][8];

    const int tid  = threadIdx.x;
    const int lane = tid & 63;
    const int wv   = tid >> 6;
    const int n0   = blockIdx.x * BM;

    const bool mbool = (mflags[0] != 0u) && (mflags[1] != 0u);
    const unsigned char* mask8  = (const unsigned char*)mask;
    const unsigned int*  mask32 = (const unsigned int*)mask;
    for (int e = tid; e < K * BM; e += 256) {
        int tap = e >> 6;
        int r   = e & (BM - 1);
        int row = n0 + r;
        unsigned int off = 0u;                         // masked / OOB -> zero page
        if (row < N) {
            size_t ei = (size_t)row * K + tap;
            bool mv = mbool ? (mask8[ei] != 0) : (mask32[ei] != 0u);
            if (mv) off = 512u + (unsigned int)nbr[ei] * 512u;
        }
        offs[tap][r] = off;
    }

    f32x4 acc[4][4];
    #pragma unroll
    for (int rt = 0; rt < 4; ++rt)
        #pragma unroll
        for (int ct = 0; ct < 4; ++ct)
            acc[rt][ct] = (f32x4){0.f, 0.f, 0.f, 0.f};

    __syncthreads();                                   // offs visible to all

    // stage s (tap = s/2, 128-ch half = s%2) into buffer b: 4 loads/wave, 1 KB each.
    // LDS dest linear (wave-uniform base + lane*16); swizzle baked into SOURCE:
    // LDS[r][slot] <- global slot (slot ^ (r&7))  (rule 21: both-sides-or-neither)
    auto stage = [&](int s, int b) {
        int tap = s >> 1, h = (s & 1) * 256;
        #pragma unroll
        for (int ii = 0; ii < 4; ++ii) {
            int i = wv * 4 + ii;                       // 0..15: 4 rows each
            int r = i * 4 + (lane >> 4);
            int c16s = ((lane & 15) ^ (r & 7)) * 16;
            const char* g = gbase + offs[tap][r] + h + c16s;
            __builtin_amdgcn_global_load_lds((const __attribute__((address_space(1))) void*)g,
                (__attribute__((address_space(3))) void*)(&Abuf[b][i * 512]), 16, 0, 0);
        }
    };

    auto compute = [&](int s, int b) {
        #pragma unroll
        for (int kk = 0; kk < 4; ++kk) {
            int kkg = s * 4 + kk;
            bf16x8 bfr[4], afr[4];
            #pragma unroll
            for (int ct = 0; ct < 4; ++ct)
                bfr[ct] = *(const bf16x8*)(Wp + (((size_t)kkg * 16 + (wv * 4 + ct)) * 64 + lane) * 8);
            #pragma unroll
            for (int rt = 0; rt < 4; ++rt) {
                int r = rt * 16 + (lane & 15);
                int c16 = kk * 4 + (lane >> 4);
                afr[rt] = *(const bf16x8*)(&Abuf[b][r * 128 + ((c16 ^ (r & 7)) * 8)]);
            }
            #pragma unroll
            for (int rt = 0; rt < 4; ++rt)
                #pragma unroll
                for (int ct = 0; ct < 4; ++ct)
                    acc[rt][ct] = __builtin_amdgcn_mfma_f32_16x16x32_bf16(afr[rt], bfr[ct], acc[rt][ct], 0, 0, 0);
        }
    };

    // prologue: two stages in flight
    stage(0, 0);
    stage(1, 1);

    int bs = 0;
    for (int s = 0; s < HSTEPS; ++s) {
        // own stage-s loads landed (4 newer allowed = stage s+1); all-wave rendezvous
        if (s < HSTEPS - 1) { asm volatile("s_waitcnt vmcnt(4)" ::: "memory"); }
        else                { asm volatile("s_waitcnt vmcnt(0)" ::: "memory"); }
        __builtin_amdgcn_sched_barrier(0);
        __builtin_amdgcn_s_barrier();                  // raw: no vmcnt drain
        __builtin_amdgcn_sched_barrier(0);
        // buffer (s+2)%3 was last read at stage s-1, all waves past that barrier
        if (s + 2 < HSTEPS) {
            int bn = bs + 2 >= NBUF ? bs + 2 - NBUF : bs + 2;
            stage(s + 2, bn);
        }
        compute(s, bs);
        __builtin_amdgcn_sched_barrier(0);
        bs = (bs + 1 == NBUF) ? 0 : bs + 1;
    }

    // ---- LayerNorm partials ----
    #pragma unroll
    for (int rt = 0; rt < 4; ++rt) {
        #pragma unroll
        for (int jj = 0; jj < 4; ++jj) {
            float p1 = 0.f, p2 = 0.f;
            #pragma unroll
            for (int ct = 0; ct < 4; ++ct) {
                float v = acc[rt][ct][jj];
                p1 += v; p2 += v * v;
            }
            #pragma unroll
            for (int off = 1; off < 16; off <<= 1) {
                p1 += __shfl_xor(p1, off, 64);
                p2 += __shfl_xor(p2, off, 64);
            }
            if ((lane & 15) == 0) {
                int row = rt * 16 + (lane >> 4) * 4 + jj;
                part[row][wv * 2]     = p1;
                part[row][wv * 2 + 1] = p2;
            }
        }
    }
    __syncthreads();

    // ---- finalize: LN + (residual) + GELU + store ----
    float gm[4], bt[4];
    #pragma unroll
    for (int ct = 0; ct < 4; ++ct) {
        int col = wv * 64 + ct * 16 + (lane & 15);
        gm[ct] = gamma[col]; bt[ct] = beta[col];
    }
    const float inv_c = 1.0f / 256.0f;
    #pragma unroll
    for (int rt = 0; rt < 4; ++rt) {
        #pragma unroll
        for (int jj = 0; jj < 4; ++jj) {
            int row = rt * 16 + (lane >> 4) * 4 + jj;
            float t1 = part[row][0] + part[row][2] + part[row][4] + part[row][6];
            float t2 = part[row][1] + part[row][3] + part[row][5] + part[row][7];
            float mu  = t1 * inv_c;
            float var = t2 * inv_c - mu * mu;
            float rs  = rsqrtf(var + 1e-6f);
            int grow = n0 + row;
            if (grow < N) {
                #pragma unroll
                for (int ct = 0; ct < 4; ++ct) {
                    int col = wv * 64 + ct * 16 + (lane & 15);
                    float x = (acc[rt][ct][jj] - mu) * rs * gm[ct] + bt[ct];
                    if (PHASE == 2) x += resid[(size_t)grow * C + col];
                    float o = gelu_exact(x);
                    if (PHASE == 1) ((unsigned short*)dst)[(size_t)grow * C + col] = f2bf(o);
                    else            ((float*)dst)[(size_t)grow * C + col] = o;
                }
            }
        }
    }
}

extern "C" void kernel_launch(void* const* d_in, const int* in_sizes, int n_in,
                              void* d_out, int out_size, void* d_ws, size_t ws_size,
                              hipStream_t stream) {
    const float* feats = (const float*)d_in[0];
    const float* W1    = (const float*)d_in[1];
    const float* g1    = (const float*)d_in[2];
    const float* b1    = (const float*)d_in[3];
    const float* W2    = (const float*)d_in[4];
    const float* g2    = (const float*)d_in[5];
    const float* b2    = (const float*)d_in[6];
    const int*   nbr   = (const int*)d_in[7];
    const void*  mask  = (const void*)d_in[8];

    const int N = in_sizes[0] / C;

    // ws: [zero 512B][h1 bf16 N*C*2][Wp1][Wp2][flags]  (~54 MB, proven budget)
    char* ws = (char*)d_ws;
    unsigned short* h1  = (unsigned short*)(ws + 512);
    size_t h1_bytes = 512 + (size_t)N * C * 2;
    size_t wp_bytes = (size_t)NKSTEP * 16 * 64 * 16;
    unsigned short* Wp1 = (unsigned short*)(ws + h1_bytes);
    unsigned short* Wp2 = (unsigned short*)(ws + h1_bytes + wp_bytes);
    unsigned int* mflags = (unsigned int*)(ws + h1_bytes + 2 * wp_bytes);

    // d_out doubles as phase-1 gather arena: [zero 512B][featsb bf16 N*C*2];
    // phase 2 overwrites it with the final fp32 output (nobody reads featsb then).
    char* fzone = (char*)d_out;
    unsigned short* featsb = (unsigned short*)(fzone + 512);

    hipMemsetAsync(ws, 0, 512, stream);
    hipMemsetAsync(fzone, 0, 512, stream);
    hipMemsetAsync(mflags, 0, 2 * sizeof(unsigned int), stream);
    detect_mask_kernel<<<256, 256, 0, stream>>>((const unsigned char*)mask, N * K, mflags);
    convert_feats<<<(N * C / 8 + 255) / 256, 256, 0, stream>>>(feats, featsb, N * C / 8);
    pack_w<<<(NKSTEP * 16 * 64 + 255) / 256, 256, 0, stream>>>(W1, Wp1);
    pack_w<<<(NKSTEP * 16 * 64 + 255) / 256, 256, 0, stream>>>(W2, Wp2);

    const int grid = (N + BM - 1) / BM;
    conv_mfma<1><<<grid, 256, 0, stream>>>(fzone, Wp1, g1, b1, nbr, mask, mflags,
                                           nullptr, (void*)h1, N);
    conv_mfma<2><<<grid, 256, 0, stream>>>(ws, Wp2, g2, b2, nbr, mask, mflags,
                                           feats, d_out, N);
}